// Round 1
// baseline (1067.221 us; speedup 1.0000x reference)
//
#include <hip/hip_runtime.h>

// Problem constants
#define M_TOK 32768   // B*L = 16*2048
#define DIM   128     // D
#define KCODES 8192   // K

// Tiling for the argmin GEMM
#define BM 64         // tokens per block
#define BN 256        // codes per tile iteration
#define BD 16         // d-chunk staged per sync
#define XS_STRIDE 68  // BM + 4 pad (byte stride 272, 16B-aligned)
#define CS_STRIDE 260 // BN + 4 pad (byte stride 1040, 16B-aligned)

// -------------------------------------------------------------------------
// Kernel 1: cnorm[k] = ||codebook[k]||^2. One wave per code.
__global__ __launch_bounds__(256) void cnorm_kernel(
    const float* __restrict__ cb, float* __restrict__ cnorm) {
    const int k = blockIdx.x * 4 + (threadIdx.x >> 6);
    const int lane = threadIdx.x & 63;
    const float2 v = ((const float2*)(cb + (size_t)k * DIM))[lane];
    float s = v.x * v.x + v.y * v.y;
    #pragma unroll
    for (int off = 32; off > 0; off >>= 1)
        s += __shfl_down(s, off);
    if (lane == 0) cnorm[k] = s;
}

// -------------------------------------------------------------------------
// Kernel 2: per-token argmin over codes of (||c||^2 - 2 x.c).
// Block: 256 threads = 8x8 score tile each over BM=64 tokens x BN=256 codes.
__global__ __launch_bounds__(256, 2) void vq_argmin_kernel(
    const float* __restrict__ ze, const float* __restrict__ cb,
    const float* __restrict__ cnorm, int* __restrict__ out_idx,
    float* __restrict__ out_idx_f) {
    __shared__ float xs[DIM * XS_STRIDE];  // x transposed: [d][m]
    __shared__ float cs[BD * CS_STRIDE];   // code chunk transposed: [dd][n]

    const int tid = threadIdx.x;
    const int m0 = blockIdx.x * BM;

    // Stage xs: z_e[m0+mm][*] -> xs[d][mm] (transpose). Coalesced float4 reads.
    {
        const int g = tid >> 3;   // d-group 0..31 (4 floats)
        const int mmb = tid & 7;  // token 0..7 per pass
        #pragma unroll
        for (int p = 0; p < 8; ++p) {
            const int mm = mmb + p * 8;
            const float4 v =
                *(const float4*)(ze + (size_t)(m0 + mm) * DIM + g * 4);
            xs[(g * 4 + 0) * XS_STRIDE + mm] = v.x;
            xs[(g * 4 + 1) * XS_STRIDE + mm] = v.y;
            xs[(g * 4 + 2) * XS_STRIDE + mm] = v.z;
            xs[(g * 4 + 3) * XS_STRIDE + mm] = v.w;
        }
    }

    const int tx = tid & 31;  // code group: codes tx*8 .. tx*8+7 within tile
    const int ty = tid >> 5;  // token group: tokens ty*8 .. ty*8+7

    float best[8];
    int bidx[8];
    #pragma unroll
    for (int i = 0; i < 8; ++i) { best[i] = 3.4e38f; bidx[i] = 0; }

    for (int n0 = 0; n0 < KCODES; n0 += BN) {
        float acc[8][8];
        #pragma unroll
        for (int i = 0; i < 8; ++i)
            #pragma unroll
            for (int j = 0; j < 8; ++j) acc[i][j] = 0.0f;

        float cn[8];
        #pragma unroll
        for (int j = 0; j < 8; ++j) cn[j] = cnorm[n0 + tx * 8 + j];

        for (int d0 = 0; d0 < DIM; d0 += BD) {
            __syncthreads();  // prior compute done (and xs staged on 1st pass)
            // Stage cs chunk: cb[n0+kk][d0..d0+15] -> cs[dd][kk] (transpose)
            {
                const int g = tid & 3;    // d-group 0..3
                const int kkb = tid >> 2; // 0..63
                #pragma unroll
                for (int p = 0; p < 4; ++p) {
                    const int kk = kkb + p * 64;
                    const float4 v = *(const float4*)(
                        cb + (size_t)(n0 + kk) * DIM + d0 + g * 4);
                    cs[(g * 4 + 0) * CS_STRIDE + kk] = v.x;
                    cs[(g * 4 + 1) * CS_STRIDE + kk] = v.y;
                    cs[(g * 4 + 2) * CS_STRIDE + kk] = v.z;
                    cs[(g * 4 + 3) * CS_STRIDE + kk] = v.w;
                }
            }
            __syncthreads();

            #pragma unroll
            for (int dd = 0; dd < BD; ++dd) {
                const float4 a0 =
                    *(const float4*)&xs[(d0 + dd) * XS_STRIDE + ty * 8];
                const float4 a1 =
                    *(const float4*)&xs[(d0 + dd) * XS_STRIDE + ty * 8 + 4];
                const float4 b0 = *(const float4*)&cs[dd * CS_STRIDE + tx * 8];
                const float4 b1 =
                    *(const float4*)&cs[dd * CS_STRIDE + tx * 8 + 4];
                const float a[8] = {a0.x, a0.y, a0.z, a0.w,
                                    a1.x, a1.y, a1.z, a1.w};
                const float b[8] = {b0.x, b0.y, b0.z, b0.w,
                                    b1.x, b1.y, b1.z, b1.w};
                #pragma unroll
                for (int i = 0; i < 8; ++i)
                    #pragma unroll
                    for (int j = 0; j < 8; ++j)
                        acc[i][j] = fmaf(a[i], b[j], acc[i][j]);
            }
        }

        // Fold tile scores into running best. Ascending j + strict < keeps
        // the lowest index on exact ties (matches jnp.argmin first-min).
        #pragma unroll
        for (int i = 0; i < 8; ++i) {
            #pragma unroll
            for (int j = 0; j < 8; ++j) {
                const float s = cn[j] - 2.0f * acc[i][j];
                const int idx = n0 + tx * 8 + j;
                if (s < best[i]) { best[i] = s; bidx[i] = idx; }
            }
        }
    }

    // Cross-thread reduction: each token m has 32 candidates (one per tx).
    __syncthreads();
    float* red_s = xs;                    // 64*32 floats
    int* red_i = (int*)(xs + BM * 32);    // 64*32 ints (fits in xs: 8704 fl)
    #pragma unroll
    for (int i = 0; i < 8; ++i) {
        const int m = ty * 8 + i;
        red_s[m * 32 + tx] = best[i];
        red_i[m * 32 + tx] = bidx[i];
    }
    __syncthreads();
    if (tid < BM) {
        const int m = tid;
        float bs = red_s[m * 32];
        int bi = red_i[m * 32];
        for (int t = 1; t < 32; ++t) {
            const float s = red_s[m * 32 + t];
            const int ix = red_i[m * 32 + t];
            if (s < bs || (s == bs && ix < bi)) { bs = s; bi = ix; }
        }
        out_idx[m0 + m] = bi;
        out_idx_f[m0 + m] = (float)bi;  // indices output (float32 buffer)
    }
}

// -------------------------------------------------------------------------
// Kernel 3: z_q[m][*] = codebook[idx[m]][*]
__global__ __launch_bounds__(256) void gather_kernel(
    const float* __restrict__ cb, const int* __restrict__ idx,
    float* __restrict__ zq) {
    const int m = blockIdx.x * 2 + (threadIdx.x >> 7);
    const int d = threadIdx.x & 127;
    zq[(size_t)m * DIM + d] = cb[(size_t)idx[m] * DIM + d];
}

// -------------------------------------------------------------------------
extern "C" void kernel_launch(void* const* d_in, const int* in_sizes, int n_in,
                              void* d_out, int out_size, void* d_ws,
                              size_t ws_size, hipStream_t stream) {
    const float* ze = (const float*)d_in[0];  // [B,L,D] fp32
    const float* cb = (const float*)d_in[1];  // [K,D]  fp32
    float* out = (float*)d_out;               // z_q (M*D) then indices (M)

    float* cnorm = (float*)d_ws;                          // K floats
    int* idx = (int*)((char*)d_ws + KCODES * sizeof(float));  // M ints

    cnorm_kernel<<<KCODES / 4, 256, 0, stream>>>(cb, cnorm);
    vq_argmin_kernel<<<M_TOK / BM, 256, 0, stream>>>(
        ze, cb, cnorm, idx, out + (size_t)M_TOK * DIM);
    gather_kernel<<<M_TOK / 2, 256, 0, stream>>>(cb, idx, out);
}

// Round 2
// 457.068 us; speedup vs baseline: 2.3349x; 2.3349x over previous
//
#include <hip/hip_runtime.h>

// VQ argmin via split-f16 MFMA: x.c = xh.ch + xh.cl + xl.ch (error ~2^-22 rel,
// ~2e-5 abs) on matrix cores, with exact-fp32 rescan for tokens whose
// best/second-best gap < MARGIN (safety net against argmin flips).

#define M_TOK  32768   // B*L
#define DIM    128
#define KCODES 8192

#define BM 64          // tokens per block
#define BN 256         // codes per n-tile (4 waves x 64)
#define NCHUNK 4       // code chunks across blockIdx.y
#define CHUNK (KCODES / NCHUNK)   // 2048
#define NT_PER (CHUNK / BN)       // 8
#define MARGIN 1e-3f   // ~50x the split-f16 max score error

typedef _Float16 half8v __attribute__((ext_vector_type(8)));
typedef float float4v __attribute__((ext_vector_type(4)));

union H2U { _Float16 h; unsigned short u; };
__device__ __forceinline__ unsigned short f2h_bits(_Float16 h) {
  H2U c; c.h = h; return c.u;
}

__device__ __forceinline__ void gload_lds16(const void* g, void* l) {
  __builtin_amdgcn_global_load_lds(
      (const __attribute__((address_space(1))) unsigned int*)g,
      (__attribute__((address_space(3))) unsigned int*)l, 16, 0, 0);
}

// ws layout: Cs f16[K][256] (hi|lo) | cnorm f32[K] | partials float4[4][M]
#define CS_BYTES   (KCODES * 256 * 2)          // 4 MiB
#define CNORM_OFF  CS_BYTES
#define PART_OFF   (CS_BYTES + KCODES * 4)     // + partials 2 MiB = 6.03 MiB

// -------------------------------------------------------------------------
// prep: cnorm (exact fp32) + split codebook into f16 hi|lo. One wave/code.
__global__ __launch_bounds__(256) void prep_kernel(
    const float* __restrict__ cb, unsigned short* __restrict__ Cs,
    float* __restrict__ cnorm) {
  const int k = blockIdx.x * 4 + (threadIdx.x >> 6);
  const int lane = threadIdx.x & 63;
  const float2 v = ((const float2*)(cb + (size_t)k * DIM))[lane];
  float s = v.x * v.x + v.y * v.y;
  #pragma unroll
  for (int off = 32; off > 0; off >>= 1) s += __shfl_down(s, off);
  if (lane == 0) cnorm[k] = s;
  const _Float16 hx = (_Float16)v.x, hy = (_Float16)v.y;
  ushort2 hi, lo;
  hi.x = f2h_bits(hx); hi.y = f2h_bits(hy);
  lo.x = f2h_bits((_Float16)(v.x - (float)hx));
  lo.y = f2h_bits((_Float16)(v.y - (float)hy));
  *(ushort2*)(Cs + (size_t)k * 256 + lane * 2) = hi;
  *(ushort2*)(Cs + (size_t)k * 256 + 128 + lane * 2) = lo;
}

// -------------------------------------------------------------------------
// Main: 64 tokens/block x 2048-code chunk. A (tokens, hi|lo f16, K=256) lives
// in LDS with 16B-seg XOR swizzle (2-way conflicts only). B staged per BK=32
// via global_load_lds (dest is lane-contiguous; swizzle applied on the
// SOURCE address so frag reads XOR-deswizzle). 2-barrier m97-style K-loop.
__global__ __launch_bounds__(256, 2) void vq_mfma_kernel(
    const float* __restrict__ ze, const unsigned short* __restrict__ Cs,
    const float* __restrict__ cnorm, float4* __restrict__ partials) {
  __shared__ char lds[57344];
  char* const As = lds;                      // 64 rows x 512 B (swizzled)
  char* const Bs = lds + 32768;              // 256 rows x 64 B
  float* const cns = (float*)(lds + 49152);  // 2048 floats

  const int tid = threadIdx.x;
  const int wave = tid >> 6;
  const int lane = tid & 63;
  const int quad = lane >> 4;
  const int l15 = lane & 15;
  const int m0 = blockIdx.x * BM;
  const int cbase = blockIdx.y * CHUNK;

  // ---- stage A: fp32 -> (xh|xl) f16, swizzled seg = (col>>3) ^ (row&7) ----
  {
    const int r = tid >> 2;
    const int qh = tid & 3;
    const float* zrow = ze + (size_t)(m0 + r) * DIM + qh * 32;
    char* arow = As + r * 512;
    const int rx = r & 7;
    #pragma unroll
    for (int i = 0; i < 8; ++i) {
      const float4 v = *(const float4*)(zrow + i * 4);
      const _Float16 h0 = (_Float16)v.x, h1 = (_Float16)v.y,
                     h2 = (_Float16)v.z, h3 = (_Float16)v.w;
      ushort4 hh, ll;
      hh.x = f2h_bits(h0); hh.y = f2h_bits(h1);
      hh.z = f2h_bits(h2); hh.w = f2h_bits(h3);
      ll.x = f2h_bits((_Float16)(v.x - (float)h0));
      ll.y = f2h_bits((_Float16)(v.y - (float)h1));
      ll.z = f2h_bits((_Float16)(v.z - (float)h2));
      ll.w = f2h_bits((_Float16)(v.w - (float)h3));
      const int c = qh * 32 + i * 4;
      *(ushort4*)(arow + ((((c >> 3) ^ rx) << 4) | ((c & 7) << 1))) = hh;
      const int c2 = c + 128;
      *(ushort4*)(arow + ((((c2 >> 3) ^ rx) << 4) | ((c2 & 7) << 1))) = ll;
    }
    #pragma unroll
    for (int p = 0; p < 2; ++p)
      ((float4*)cns)[tid + p * 256] =
          ((const float4*)(cnorm + cbase))[tid + p * 256];
  }

  // Running per-lane argmin state: 16 token rows (i,reg), value/sec/idx.
  float bestv[16], secv[16], idxv[16];
  #pragma unroll
  for (int s = 0; s < 16; ++s) {
    bestv[s] = 3.4e38f; secv[s] = 3.4e38f; idxv[s] = 0.f;
  }

  const int wn = wave;  // wave's 64-code column strip within the 256-tile

  for (int nt = 0; nt < NT_PER; ++nt) {
    const int n0 = nt * BN;
    float4v acc[4][4];
    #pragma unroll
    for (int i = 0; i < 4; ++i)
      #pragma unroll
      for (int j = 0; j < 4; ++j) acc[i][j] = (float4v)0.0f;

    for (int kk = 0; kk < 8; ++kk) {
      __syncthreads();  // prior Bs reads complete before DMA overwrite
      // B k-columns: kk<4 -> ch seg (cols kk*32), kk>=4 -> cl seg
      const int col0 = (kk < 4) ? kk * 32 : 128 + (kk - 4) * 32;
      #pragma unroll
      for (int c = 0; c < 4; ++c) {
        const int g = wave * 256 + c * 64 + lane;  // linear 16B seg id
        const int r = g >> 2, s = g & 3;
        const unsigned short* gp = Cs + (size_t)(cbase + n0 + r) * 256 +
                                   col0 + ((s ^ ((r >> 1) & 3)) << 3);
        gload_lds16(gp, Bs + (wave * 4 + c) * 1024);  // wave-uniform dest
      }
      __syncthreads();  // drains vmcnt -> Bs ready

      half8v bf[4];
      #pragma unroll
      for (int j = 0; j < 4; ++j) {
        const int n = wn * 64 + j * 16 + l15;
        bf[j] = *(half8v*)(Bs + n * 64 + ((quad ^ ((n >> 1) & 3)) << 4));
      }
      // A passes: vs ch use xh AND xl (2 passes); vs cl use xh only.
      const int ka0 = (kk < 4) ? kk * 32 : (kk - 4) * 32;
      const int passes = (kk < 4) ? 2 : 1;
      for (int p = 0; p < passes; ++p) {
        const int ka = ka0 + p * 128;
        half8v af[4];
        #pragma unroll
        for (int i = 0; i < 4; ++i) {
          const int m = i * 16 + l15;
          const int kslot = (ka >> 3) + quad;
          af[i] = *(half8v*)(As + m * 512 + ((kslot ^ (m & 7)) << 4));
        }
        #pragma unroll
        for (int i = 0; i < 4; ++i)
          #pragma unroll
          for (int j = 0; j < 4; ++j)
            acc[i][j] = __builtin_amdgcn_mfma_f32_16x16x32_f16(
                af[i], bf[j], acc[i][j], 0, 0, 0);
      }
    }

    // Fold scores. Ascending n within lane; strict < keeps lowest index.
    #pragma unroll
    for (int j = 0; j < 4; ++j) {
      const int ncol = n0 + wn * 64 + j * 16 + l15;
      const float cn = cns[ncol];
      const float nidx = (float)(cbase + ncol);
      #pragma unroll
      for (int i = 0; i < 4; ++i)
        #pragma unroll
        for (int rg = 0; rg < 4; ++rg) {
          const float sc = fmaf(-2.0f, acc[i][j][rg], cn);
          const int slot = i * 4 + rg;
          const bool bf2 = sc < bestv[slot];
          secv[slot] = bf2 ? bestv[slot] : fminf(secv[slot], sc);
          idxv[slot] = bf2 ? nidx : idxv[slot];
          bestv[slot] = bf2 ? sc : bestv[slot];
        }
    }
  }

  // Cross-lane reduce: row lives in 16 lanes (same quad group). xor 1,2,4,8.
  #pragma unroll
  for (int slot = 0; slot < 16; ++slot) {
    float b = bestv[slot], sec = secv[slot], ix = idxv[slot];
    #pragma unroll
    for (int mk = 1; mk <= 8; mk <<= 1) {
      const float ob = __shfl_xor(b, mk);
      const float os = __shfl_xor(sec, mk);
      const float oi = __shfl_xor(ix, mk);
      const bool take = (ob < b) || (ob == b && oi < ix);
      const float loser = take ? b : ob;
      b = take ? ob : b;
      ix = take ? oi : ix;
      sec = fminf(fminf(sec, os), loser);
    }
    bestv[slot] = b; secv[slot] = sec; idxv[slot] = ix;
  }

  // Cross-wave merge via LDS (reuse As region after barrier).
  __syncthreads();
  float* const redB = (float*)lds;
  float* const redS = redB + 256;
  float* const redI = redS + 256;
  if (l15 == 0) {
    #pragma unroll
    for (int slot = 0; slot < 16; ++slot) {
      const int row = (slot >> 2) * 16 + quad * 4 + (slot & 3);
      redB[wn * 64 + row] = bestv[slot];
      redS[wn * 64 + row] = secv[slot];
      redI[wn * 64 + row] = idxv[slot];
    }
  }
  __syncthreads();
  if (tid < 64) {
    const int row = tid;
    float b = redB[row], sec = redS[row], ix = redI[row];
    #pragma unroll
    for (int w = 1; w < 4; ++w) {
      const float ob = redB[w * 64 + row];
      const float os = redS[w * 64 + row];
      const float oi = redI[w * 64 + row];
      const bool take = (ob < b) || (ob == b && oi < ix);
      const float loser = take ? b : ob;
      b = take ? ob : b;
      ix = take ? oi : ix;
      sec = fminf(fminf(sec, os), loser);
    }
    partials[(size_t)blockIdx.y * M_TOK + m0 + row] =
        make_float4(b, sec, ix, 0.f);
  }
}

// -------------------------------------------------------------------------
// finalize: merge 4 chunk partials; exact fp32 rescan if gap < MARGIN;
// write idx (as float) and gather z_q rows from the fp32 codebook.
__global__ __launch_bounds__(256) void finalize_kernel(
    const float* __restrict__ ze, const float* __restrict__ cb,
    const float* __restrict__ cnorm, const float4* __restrict__ partials,
    float* __restrict__ out_zq, float* __restrict__ out_idx) {
  __shared__ float lidx[64];
  __shared__ int lflag[64];
  __shared__ float xsh[128];
  __shared__ float rs[256];
  __shared__ int ri[256];
  const int tid = threadIdx.x;
  const int t0 = blockIdx.x * 64;

  if (tid < 64) {
    const int token = t0 + tid;
    float4 p = partials[token];
    float b = p.x, sec = p.y, ix = p.z;
    #pragma unroll
    for (int c = 1; c < NCHUNK; ++c) {
      const float4 q = partials[(size_t)c * M_TOK + token];
      const bool take = (q.x < b) || (q.x == b && q.z < ix);
      const float loser = take ? b : q.x;
      b = take ? q.x : b;
      ix = take ? q.z : ix;
      sec = fminf(fminf(sec, q.y), loser);
    }
    lidx[tid] = ix;
    lflag[tid] = (sec - b) < MARGIN ? 1 : 0;
  }
  __syncthreads();

  for (int t = 0; t < 64; ++t) {
    if (lflag[t]) {  // block-uniform branch
      if (tid < 32)
        ((float4*)xsh)[tid] = ((const float4*)(ze + (size_t)(t0 + t) * DIM))[tid];
      __syncthreads();
      float bs = 3.4e38f;
      int bi = 0;
      for (int i = 0; i < 32; ++i) {
        const int code = tid + (i << 8);
        const float* crow = cb + (size_t)code * DIM;
        float dot = 0.f;
        #pragma unroll
        for (int d = 0; d < DIM; ++d) dot = fmaf(xsh[d], crow[d], dot);
        const float s = fmaf(-2.f, dot, cnorm[code]);
        if (s < bs) { bs = s; bi = code; }
      }
      rs[tid] = bs; ri[tid] = bi;
      __syncthreads();
      if (tid == 0) {
        float b2 = rs[0];
        int i2 = ri[0];
        for (int u = 1; u < 256; ++u)
          if (rs[u] < b2 || (rs[u] == b2 && ri[u] < i2)) { b2 = rs[u]; i2 = ri[u]; }
        lidx[t] = (float)i2;
      }
      __syncthreads();
    }
  }
  __syncthreads();

  if (tid < 64) out_idx[t0 + tid] = lidx[tid];
  const int tl = tid >> 2;
  const int qp = tid & 3;
  const int code = (int)lidx[tl];
  const float4* src = (const float4*)(cb + (size_t)code * DIM);
  float4* dst = (float4*)(out_zq + (size_t)(t0 + tl) * DIM);
  #pragma unroll
  for (int p = 0; p < 8; ++p) dst[qp + p * 4] = src[qp + p * 4];
}

// -------------------------------------------------------------------------
extern "C" void kernel_launch(void* const* d_in, const int* in_sizes, int n_in,
                              void* d_out, int out_size, void* d_ws,
                              size_t ws_size, hipStream_t stream) {
  const float* ze = (const float*)d_in[0];
  const float* cb = (const float*)d_in[1];
  float* out = (float*)d_out;

  unsigned short* Cs = (unsigned short*)d_ws;
  float* cnorm = (float*)((char*)d_ws + CNORM_OFF);
  float4* partials = (float4*)((char*)d_ws + PART_OFF);

  prep_kernel<<<KCODES / 4, 256, 0, stream>>>(cb, Cs, cnorm);
  vq_mfma_kernel<<<dim3(M_TOK / BM, NCHUNK), 256, 0, stream>>>(
      ze, Cs, cnorm, partials);
  finalize_kernel<<<M_TOK / 64, 256, 0, stream>>>(
      ze, cb, cnorm, partials, out, out + (size_t)M_TOK * DIM);
}

// Round 4
// 421.678 us; speedup vs baseline: 2.5309x; 1.0839x over previous
//
#include <hip/hip_runtime.h>

// VQ argmin via split-f16 MFMA (x.c = xh.ch + xl.ch + xh.cl), verified R2
// 2-barrier K-loop structure. Score = cn - 2*dot folded in fp32 epilogue.
// One block owns all 8192 codes for its 64 tokens (no partials/finalize);
// ambiguous tokens (best2-best1 < MARGIN) re-scanned exactly in fp32.

#define M_TOK  32768
#define DIM    128
#define KCODES 8192
#define BM     64
#define NT     (KCODES / 256)   // 32 n-tiles per block
#define MARGIN 1e-3f

typedef _Float16 half8v __attribute__((ext_vector_type(8)));
typedef float float4v __attribute__((ext_vector_type(4)));

union H2U { _Float16 h; unsigned short u; };
__device__ __forceinline__ unsigned short f2h_bits(_Float16 h) {
  H2U c; c.h = h; return c.u;
}

__device__ __forceinline__ void gload_lds16(const void* g, void* l) {
  __builtin_amdgcn_global_load_lds(
      (const __attribute__((address_space(1))) unsigned int*)g,
      (__attribute__((address_space(3))) unsigned int*)l, 16, 0, 0);
}

// ws layout: Cs f16[K][256] (hi|lo) | cnorm f32[K] | qcnt | qtok
#define CNORM_OFF  (KCODES * 512)
#define QCNT_OFF   (CNORM_OFF + KCODES * 4)
#define QTOK_OFF   (QCNT_OFF + 64)

// -------------------------------------------------------------------------
// prep: exact fp32 cnorm + split codebook into f16 hi|lo rows. Zeroes qcnt.
__global__ __launch_bounds__(256) void prep_kernel(
    const float* __restrict__ cb, unsigned short* __restrict__ Cs,
    float* __restrict__ cnorm, int* __restrict__ qcnt) {
  if (blockIdx.x == 0 && threadIdx.x == 0) *qcnt = 0;
  const int k = blockIdx.x * 4 + (threadIdx.x >> 6);
  const int lane = threadIdx.x & 63;
  const float2 v = ((const float2*)(cb + (size_t)k * DIM))[lane];
  float s = v.x * v.x + v.y * v.y;
  #pragma unroll
  for (int off = 32; off > 0; off >>= 1) s += __shfl_down(s, off);
  if (lane == 0) cnorm[k] = s;
  const _Float16 hx = (_Float16)v.x, hy = (_Float16)v.y;
  ushort2 hi, lo;
  hi.x = f2h_bits(hx); hi.y = f2h_bits(hy);
  lo.x = f2h_bits((_Float16)(v.x - (float)hx));
  lo.y = f2h_bits((_Float16)(v.y - (float)hy));
  *(ushort2*)(Cs + (size_t)k * 256 + lane * 2) = hi;
  *(ushort2*)(Cs + (size_t)k * 256 + 128 + lane * 2) = lo;
}

// -------------------------------------------------------------------------
__global__ __launch_bounds__(256, 2) void vq_mfma_kernel(
    const float* __restrict__ ze, const unsigned short* __restrict__ Cs,
    const float* __restrict__ cnorm, const float* __restrict__ cb,
    int* __restrict__ qcnt, int* __restrict__ qtok,
    float* __restrict__ out_zq, float* __restrict__ out_idx) {
  __shared__ char lds[49152];
  char* const As = lds;            // 32 KB: 64 rows x 512 B, seg-XOR swizzled
  char* const Bs = lds + 32768;    // 16 KB: 4 waves x 4 KB (private slices)

  const int tid = threadIdx.x;
  const int wn = tid >> 6;
  const int lane = tid & 63;
  const int quad = lane >> 4;
  const int l15 = lane & 15;
  const int m0 = blockIdx.x * BM;

  // Per-lane B-staging source offsets (R2-verified mapping).
  // Dest slot s of local row r holds source seg (s ^ ((r>>1)&3)).
  int loffC[4];
  #pragma unroll
  for (int c = 0; c < 4; ++c) {
    const int r = c * 16 + (lane >> 2);       // local row 0..63
    const int s = lane & 3;
    const int seg = s ^ ((r >> 1) & 3);
    loffC[c] = (wn * 64 + r) * 512 + seg * 16;  // bytes within tile
  }
  int boff[4];
  #pragma unroll
  for (int j = 0; j < 4; ++j) {
    const int n = j * 16 + l15;
    boff[j] = n * 64 + ((quad ^ ((n >> 1) & 3)) << 4);
  }
  char* const BsW = Bs + wn * 4096;

  // ---- stage As: fp32 -> (xh|xl) f16, seg = (col>>3) ^ (row&7) ----
  {
    const int r = tid >> 2;
    const int qh = tid & 3;
    const float* zrow = ze + (size_t)(m0 + r) * DIM + qh * 32;
    char* arow = As + r * 512;
    const int rx = r & 7;
    #pragma unroll
    for (int i = 0; i < 8; ++i) {
      const float4 v = *(const float4*)(zrow + i * 4);
      const _Float16 h0 = (_Float16)v.x, h1 = (_Float16)v.y,
                     h2 = (_Float16)v.z, h3 = (_Float16)v.w;
      ushort4 hh, ll;
      hh.x = f2h_bits(h0); hh.y = f2h_bits(h1);
      hh.z = f2h_bits(h2); hh.w = f2h_bits(h3);
      ll.x = f2h_bits((_Float16)(v.x - (float)h0));
      ll.y = f2h_bits((_Float16)(v.y - (float)h1));
      ll.z = f2h_bits((_Float16)(v.z - (float)h2));
      ll.w = f2h_bits((_Float16)(v.w - (float)h3));
      const int c = qh * 32 + i * 4;
      *(ushort4*)(arow + ((((c >> 3) ^ rx) << 4) | ((c & 7) << 1))) = hh;
      const int c2 = c + 128;
      *(ushort4*)(arow + ((((c2 >> 3) ^ rx) << 4) | ((c2 & 7) << 1))) = ll;
    }
  }
  __syncthreads();

  // Preload A-hi fragments into registers (reused for all 32 n-tiles).
  half8v ahi[4][4];
  #pragma unroll
  for (int ks = 0; ks < 4; ++ks)
    #pragma unroll
    for (int i = 0; i < 4; ++i) {
      const int m = i * 16 + l15;
      const int kslot = ks * 4 + quad;
      ahi[ks][i] = *(const half8v*)(As + m * 512 + ((kslot ^ (m & 7)) << 4));
    }

  float bestv[16], secv[16], idxv[16];
  #pragma unroll
  for (int s = 0; s < 16; ++s) {
    bestv[s] = 3.4e38f; secv[s] = 3.4e38f; idxv[s] = 0.f;
  }

  for (int nt = 0; nt < NT; ++nt) {
    const char* const tile = (const char*)Cs + (size_t)nt * 131072;
    // cnorm for this wave's 64-code strip (L2-resident, 4 loads/lane).
    float cnv[4];
    #pragma unroll
    for (int j = 0; j < 4; ++j)
      cnv[j] = cnorm[nt * 256 + wn * 64 + j * 16 + l15];

    float4v acc[4][4];
    #pragma unroll
    for (int i = 0; i < 4; ++i)
      #pragma unroll
      for (int j = 0; j < 4; ++j) acc[i][j] = (float4v)0.0f;

    #pragma unroll
    for (int kk = 0; kk < 8; ++kk) {
      __syncthreads();  // prior slice consumed before DMA overwrite
      #pragma unroll
      for (int c = 0; c < 4; ++c)
        gload_lds16(tile + kk * 64 + loffC[c], BsW + c * 1024);
      __syncthreads();  // drains vmcnt -> slice ready

      half8v bf[4];
      #pragma unroll
      for (int j = 0; j < 4; ++j) bf[j] = *(const half8v*)(BsW + boff[j]);

      if (kk < 4) {
        // B = ch slice kk: xh.ch (registers) + xl.ch (LDS)
        #pragma unroll
        for (int i = 0; i < 4; ++i)
          #pragma unroll
          for (int j = 0; j < 4; ++j)
            acc[i][j] = __builtin_amdgcn_mfma_f32_16x16x32_f16(
                ahi[kk][i], bf[j], acc[i][j], 0, 0, 0);
        half8v alo[4];
        #pragma unroll
        for (int i = 0; i < 4; ++i) {
          const int m = i * 16 + l15;
          const int kslot = 16 + kk * 4 + quad;
          alo[i] = *(const half8v*)(As + m * 512 + ((kslot ^ (m & 7)) << 4));
        }
        #pragma unroll
        for (int i = 0; i < 4; ++i)
          #pragma unroll
          for (int j = 0; j < 4; ++j)
            acc[i][j] = __builtin_amdgcn_mfma_f32_16x16x32_f16(
                alo[i], bf[j], acc[i][j], 0, 0, 0);
      } else {
        // B = cl slice kk-4: xh.cl (registers only)
        #pragma unroll
        for (int i = 0; i < 4; ++i)
          #pragma unroll
          for (int j = 0; j < 4; ++j)
            acc[i][j] = __builtin_amdgcn_mfma_f32_16x16x32_f16(
                ahi[kk - 4][i], bf[j], acc[i][j], 0, 0, 0);
      }
    }

    // Fold: sc = cn - 2*dot. Ascending n, strict < -> lowest index on ties.
    #pragma unroll
    for (int j = 0; j < 4; ++j) {
      const float nidx = (float)(nt * 256 + wn * 64 + j * 16 + l15);
      const float cn = cnv[j];
      #pragma unroll
      for (int i = 0; i < 4; ++i)
        #pragma unroll
        for (int rg = 0; rg < 4; ++rg) {
          const float sc = fmaf(-2.0f, acc[i][j][rg], cn);
          const int slot = i * 4 + rg;
          const bool bt = sc < bestv[slot];
          secv[slot] = bt ? bestv[slot] : fminf(secv[slot], sc);
          idxv[slot] = bt ? nidx : idxv[slot];
          bestv[slot] = bt ? sc : bestv[slot];
        }
    }
  }

  // Cross-lane reduce (16 lanes per token row, tie -> lowest index).
  #pragma unroll
  for (int slot = 0; slot < 16; ++slot) {
    float b = bestv[slot], sec = secv[slot], ix = idxv[slot];
    #pragma unroll
    for (int mk = 1; mk <= 8; mk <<= 1) {
      const float ob = __shfl_xor(b, mk);
      const float os = __shfl_xor(sec, mk);
      const float oi = __shfl_xor(ix, mk);
      const bool take = (ob < b) || (ob == b && oi < ix);
      const float loser = take ? b : ob;
      b = take ? ob : b;
      ix = take ? oi : ix;
      sec = fminf(fminf(sec, os), loser);
    }
    bestv[slot] = b; secv[slot] = sec; idxv[slot] = ix;
  }

  // Cross-wave merge via LDS (reuse As region after barrier).
  __syncthreads();
  float* const redB = (float*)lds;
  float* const redS = redB + 256;
  float* const redI = redB + 512;
  float* const lidxs = redB + 768;
  if (l15 == 0) {
    #pragma unroll
    for (int slot = 0; slot < 16; ++slot) {
      const int row = (slot >> 2) * 16 + quad * 4 + (slot & 3);
      redB[wn * 64 + row] = bestv[slot];
      redS[wn * 64 + row] = secv[slot];
      redI[wn * 64 + row] = idxv[slot];
    }
  }
  __syncthreads();
  if (tid < 64) {
    float b = redB[tid], sec = redS[tid], ix = redI[tid];
    #pragma unroll
    for (int w = 1; w < 4; ++w) {
      const float ob = redB[w * 64 + tid];
      const float os = redS[w * 64 + tid];
      const float oi = redI[w * 64 + tid];
      const bool take = (ob < b) || (ob == b && oi < ix);
      const float loser = take ? b : ob;
      b = take ? ob : b;
      ix = take ? oi : ix;
      sec = fminf(fminf(sec, os), loser);
    }
    out_idx[m0 + tid] = ix;
    lidxs[tid] = ix;
    if (sec - b < MARGIN) {  // ambiguous -> exact rescan queue
      const int p = atomicAdd(qcnt, 1);
      qtok[p] = m0 + tid;
    }
  }
  __syncthreads();

  // z_q gather for this block's 64 tokens.
  const int tl = tid >> 2, qp = tid & 3;
  const int code = (int)lidxs[tl];
  const float4* src = (const float4*)(cb + (size_t)code * DIM);
  float4* dst = (float4*)(out_zq + (size_t)(m0 + tl) * DIM);
  #pragma unroll
  for (int p = 0; p < 8; ++p) dst[qp + p * 4] = src[qp + p * 4];
}

// -------------------------------------------------------------------------
// Exact fp32 rescan of queued ambiguous tokens (expected ~0-30 total).
__global__ __launch_bounds__(256) void rescan_kernel(
    const float* __restrict__ ze, const float* __restrict__ cb,
    const float* __restrict__ cnorm, const int* __restrict__ qcnt,
    const int* __restrict__ qtok, float* __restrict__ out_zq,
    float* __restrict__ out_idx) {
  __shared__ float xsh[DIM];
  __shared__ float rs[256];
  __shared__ int ri[256];
  const int tid = threadIdx.x;
  const int n = *qcnt;
  for (int qi = blockIdx.x; qi < n; qi += gridDim.x) {
    const int token = qtok[qi];
    __syncthreads();
    if (tid < 32)
      ((float4*)xsh)[tid] = ((const float4*)(ze + (size_t)token * DIM))[tid];
    __syncthreads();
    float bs = 3.4e38f;
    int bi = 0;
    for (int i = 0; i < 32; ++i) {
      const int code = tid + (i << 8);
      const float* crow = cb + (size_t)code * DIM;
      float dot = 0.f;
      #pragma unroll
      for (int d = 0; d < DIM; ++d) dot = fmaf(xsh[d], crow[d], dot);
      const float s = fmaf(-2.f, dot, cnorm[code]);
      if (s < bs) { bs = s; bi = code; }
    }
    rs[tid] = bs; ri[tid] = bi;
    __syncthreads();
    if (tid == 0) {
      float b2 = rs[0];
      int i2 = ri[0];
      for (int u = 1; u < 256; ++u)
        if (rs[u] < b2 || (rs[u] == b2 && ri[u] < i2)) { b2 = rs[u]; i2 = ri[u]; }
      out_idx[token] = (float)i2;
      ri[0] = i2;
    }
    __syncthreads();
    const int code2 = ri[0];
    if (tid < 32)
      ((float4*)(out_zq + (size_t)token * DIM))[tid] =
          ((const float4*)(cb + (size_t)code2 * DIM))[tid];
  }
}

// -------------------------------------------------------------------------
extern "C" void kernel_launch(void* const* d_in, const int* in_sizes, int n_in,
                              void* d_out, int out_size, void* d_ws,
                              size_t ws_size, hipStream_t stream) {
  const float* ze = (const float*)d_in[0];
  const float* cb = (const float*)d_in[1];
  float* out = (float*)d_out;

  unsigned short* Cs = (unsigned short*)d_ws;
  float* cnorm = (float*)((char*)d_ws + CNORM_OFF);
  int* qcnt = (int*)((char*)d_ws + QCNT_OFF);
  int* qtok = (int*)((char*)d_ws + QTOK_OFF);

  prep_kernel<<<KCODES / 4, 256, 0, stream>>>(cb, Cs, cnorm, qcnt);
  vq_mfma_kernel<<<M_TOK / BM, 256, 0, stream>>>(
      ze, Cs, cnorm, cb, qcnt, qtok, out, out + (size_t)M_TOK * DIM);
  rescan_kernel<<<128, 256, 0, stream>>>(ze, cb, cnorm, qcnt, qtok, out,
                                         out + (size_t)M_TOK * DIM);
}

// Round 5
// 284.594 us; speedup vs baseline: 3.7500x; 1.4817x over previous
//
#include <hip/hip_runtime.h>

// VQ argmin via split-f16 MFMA (x.c = xh.ch + xl.ch + xh.cl), verified R2/R4
// 2-barrier K-loop. One block owns all 8192 codes for its 64 tokens.
// Ambiguous tokens (best2-best1 < MARGIN) re-scanned exactly in fp32 by a
// PARALLEL token-x-chunk rescan merged with atomicMin on packed (score,idx).

#define M_TOK  32768
#define DIM    128
#define KCODES 8192
#define BM     64
#define NT     (KCODES / 256)   // 32 n-tiles per block
#define MARGIN 3e-4f            // >=10 sigma of split-f16 score error

typedef _Float16 half8v __attribute__((ext_vector_type(8)));
typedef float float4v __attribute__((ext_vector_type(4)));

union H2U { _Float16 h; unsigned short u; };
__device__ __forceinline__ unsigned short f2h_bits(_Float16 h) {
  H2U c; c.h = h; return c.u;
}

__device__ __forceinline__ void gload_lds16(const void* g, void* l) {
  __builtin_amdgcn_global_load_lds(
      (const __attribute__((address_space(1))) unsigned int*)g,
      (__attribute__((address_space(3))) unsigned int*)l, 16, 0, 0);
}

// Monotone float->u32 map: lower score -> smaller key.
__device__ __forceinline__ unsigned int fmap(float f) {
  union { float f; unsigned int u; } c; c.f = f;
  return (c.u >> 31) ? ~c.u : (c.u | 0x80000000u);
}

// ws layout: Cs f16[K][256] (hi|lo) | cnorm f32[K] | qcnt | qtok | kmin
#define CNORM_OFF  (KCODES * 512)
#define QCNT_OFF   (CNORM_OFF + KCODES * 4)
#define QTOK_OFF   (QCNT_OFF + 64)
#define KMIN_OFF   (QTOK_OFF + M_TOK * 4)

// -------------------------------------------------------------------------
// prep: exact fp32 cnorm + split codebook into f16 hi|lo rows. Zeroes qcnt.
__global__ __launch_bounds__(256) void prep_kernel(
    const float* __restrict__ cb, unsigned short* __restrict__ Cs,
    float* __restrict__ cnorm, int* __restrict__ qcnt) {
  if (blockIdx.x == 0 && threadIdx.x == 0) *qcnt = 0;
  const int k = blockIdx.x * 4 + (threadIdx.x >> 6);
  const int lane = threadIdx.x & 63;
  const float2 v = ((const float2*)(cb + (size_t)k * DIM))[lane];
  float s = v.x * v.x + v.y * v.y;
  #pragma unroll
  for (int off = 32; off > 0; off >>= 1) s += __shfl_down(s, off);
  if (lane == 0) cnorm[k] = s;
  const _Float16 hx = (_Float16)v.x, hy = (_Float16)v.y;
  ushort2 hi, lo;
  hi.x = f2h_bits(hx); hi.y = f2h_bits(hy);
  lo.x = f2h_bits((_Float16)(v.x - (float)hx));
  lo.y = f2h_bits((_Float16)(v.y - (float)hy));
  *(ushort2*)(Cs + (size_t)k * 256 + lane * 2) = hi;
  *(ushort2*)(Cs + (size_t)k * 256 + 128 + lane * 2) = lo;
}

// -------------------------------------------------------------------------
__global__ __launch_bounds__(256, 2) void vq_mfma_kernel(
    const float* __restrict__ ze, const unsigned short* __restrict__ Cs,
    const float* __restrict__ cnorm, const float* __restrict__ cb,
    int* __restrict__ qcnt, int* __restrict__ qtok,
    unsigned long long* __restrict__ kmin,
    float* __restrict__ out_zq, float* __restrict__ out_idx) {
  __shared__ char lds[49152];
  char* const As = lds;            // 32 KB: 64 rows x 512 B, seg-XOR swizzled
  char* const Bs = lds + 32768;    // 16 KB: 4 waves x 4 KB (private slices)

  const int tid = threadIdx.x;
  const int wn = tid >> 6;
  const int lane = tid & 63;
  const int quad = lane >> 4;
  const int l15 = lane & 15;
  const int m0 = blockIdx.x * BM;

  // Per-lane B-staging source offsets (R2-verified mapping).
  int loffC[4];
  #pragma unroll
  for (int c = 0; c < 4; ++c) {
    const int r = c * 16 + (lane >> 2);
    const int s = lane & 3;
    const int seg = s ^ ((r >> 1) & 3);
    loffC[c] = (wn * 64 + r) * 512 + seg * 16;
  }
  int boff[4];
  #pragma unroll
  for (int j = 0; j < 4; ++j) {
    const int n = j * 16 + l15;
    boff[j] = n * 64 + ((quad ^ ((n >> 1) & 3)) << 4);
  }
  char* const BsW = Bs + wn * 4096;

  // ---- stage As: fp32 -> (xh|xl) f16, seg = (col>>3) ^ (row&7) ----
  {
    const int r = tid >> 2;
    const int qh = tid & 3;
    const float* zrow = ze + (size_t)(m0 + r) * DIM + qh * 32;
    char* arow = As + r * 512;
    const int rx = r & 7;
    #pragma unroll
    for (int i = 0; i < 8; ++i) {
      const float4 v = *(const float4*)(zrow + i * 4);
      const _Float16 h0 = (_Float16)v.x, h1 = (_Float16)v.y,
                     h2 = (_Float16)v.z, h3 = (_Float16)v.w;
      ushort4 hh, ll;
      hh.x = f2h_bits(h0); hh.y = f2h_bits(h1);
      hh.z = f2h_bits(h2); hh.w = f2h_bits(h3);
      ll.x = f2h_bits((_Float16)(v.x - (float)h0));
      ll.y = f2h_bits((_Float16)(v.y - (float)h1));
      ll.z = f2h_bits((_Float16)(v.z - (float)h2));
      ll.w = f2h_bits((_Float16)(v.w - (float)h3));
      const int c = qh * 32 + i * 4;
      *(ushort4*)(arow + ((((c >> 3) ^ rx) << 4) | ((c & 7) << 1))) = hh;
      const int c2 = c + 128;
      *(ushort4*)(arow + ((((c2 >> 3) ^ rx) << 4) | ((c2 & 7) << 1))) = ll;
    }
  }
  __syncthreads();

  // Preload A-hi fragments into registers (reused for all 32 n-tiles).
  half8v ahi[4][4];
  #pragma unroll
  for (int ks = 0; ks < 4; ++ks)
    #pragma unroll
    for (int i = 0; i < 4; ++i) {
      const int m = i * 16 + l15;
      const int kslot = ks * 4 + quad;
      ahi[ks][i] = *(const half8v*)(As + m * 512 + ((kslot ^ (m & 7)) << 4));
    }

  float bestv[16], secv[16], idxv[16];
  #pragma unroll
  for (int s = 0; s < 16; ++s) {
    bestv[s] = 3.4e38f; secv[s] = 3.4e38f; idxv[s] = 0.f;
  }

  for (int nt = 0; nt < NT; ++nt) {
    const char* const tile = (const char*)Cs + (size_t)nt * 131072;
    float cnv[4];
    #pragma unroll
    for (int j = 0; j < 4; ++j)
      cnv[j] = cnorm[nt * 256 + wn * 64 + j * 16 + l15];

    float4v acc[4][4];
    #pragma unroll
    for (int i = 0; i < 4; ++i)
      #pragma unroll
      for (int j = 0; j < 4; ++j) acc[i][j] = (float4v)0.0f;

    #pragma unroll
    for (int kk = 0; kk < 8; ++kk) {
      __syncthreads();
      #pragma unroll
      for (int c = 0; c < 4; ++c)
        gload_lds16(tile + kk * 64 + loffC[c], BsW + c * 1024);
      __syncthreads();

      half8v bf[4];
      #pragma unroll
      for (int j = 0; j < 4; ++j) bf[j] = *(const half8v*)(BsW + boff[j]);

      if (kk < 4) {
        #pragma unroll
        for (int i = 0; i < 4; ++i)
          #pragma unroll
          for (int j = 0; j < 4; ++j)
            acc[i][j] = __builtin_amdgcn_mfma_f32_16x16x32_f16(
                ahi[kk][i], bf[j], acc[i][j], 0, 0, 0);
        half8v alo[4];
        #pragma unroll
        for (int i = 0; i < 4; ++i) {
          const int m = i * 16 + l15;
          const int kslot = 16 + kk * 4 + quad;
          alo[i] = *(const half8v*)(As + m * 512 + ((kslot ^ (m & 7)) << 4));
        }
        #pragma unroll
        for (int i = 0; i < 4; ++i)
          #pragma unroll
          for (int j = 0; j < 4; ++j)
            acc[i][j] = __builtin_amdgcn_mfma_f32_16x16x32_f16(
                alo[i], bf[j], acc[i][j], 0, 0, 0);
      } else {
        #pragma unroll
        for (int i = 0; i < 4; ++i)
          #pragma unroll
          for (int j = 0; j < 4; ++j)
            acc[i][j] = __builtin_amdgcn_mfma_f32_16x16x32_f16(
                ahi[kk - 4][i], bf[j], acc[i][j], 0, 0, 0);
      }
    }

    #pragma unroll
    for (int j = 0; j < 4; ++j) {
      const float nidx = (float)(nt * 256 + wn * 64 + j * 16 + l15);
      const float cn = cnv[j];
      #pragma unroll
      for (int i = 0; i < 4; ++i)
        #pragma unroll
        for (int rg = 0; rg < 4; ++rg) {
          const float sc = fmaf(-2.0f, acc[i][j][rg], cn);
          const int slot = i * 4 + rg;
          const bool bt = sc < bestv[slot];
          secv[slot] = bt ? bestv[slot] : fminf(secv[slot], sc);
          idxv[slot] = bt ? nidx : idxv[slot];
          bestv[slot] = bt ? sc : bestv[slot];
        }
    }
  }

  // Cross-lane reduce (16 lanes per token row, tie -> lowest index).
  #pragma unroll
  for (int slot = 0; slot < 16; ++slot) {
    float b = bestv[slot], sec = secv[slot], ix = idxv[slot];
    #pragma unroll
    for (int mk = 1; mk <= 8; mk <<= 1) {
      const float ob = __shfl_xor(b, mk);
      const float os = __shfl_xor(sec, mk);
      const float oi = __shfl_xor(ix, mk);
      const bool take = (ob < b) || (ob == b && oi < ix);
      const float loser = take ? b : ob;
      b = take ? ob : b;
      ix = take ? oi : ix;
      sec = fminf(fminf(sec, os), loser);
    }
    bestv[slot] = b; secv[slot] = sec; idxv[slot] = ix;
  }

  // Cross-wave merge via LDS (reuse As region after barrier).
  __syncthreads();
  float* const redB = (float*)lds;
  float* const redS = redB + 256;
  float* const redI = redB + 512;
  float* const lidxs = redB + 768;
  if (l15 == 0) {
    #pragma unroll
    for (int slot = 0; slot < 16; ++slot) {
      const int row = (slot >> 2) * 16 + quad * 4 + (slot & 3);
      redB[wn * 64 + row] = bestv[slot];
      redS[wn * 64 + row] = secv[slot];
      redI[wn * 64 + row] = idxv[slot];
    }
  }
  __syncthreads();
  if (tid < 64) {
    float b = redB[tid], sec = redS[tid], ix = redI[tid];
    #pragma unroll
    for (int w = 1; w < 4; ++w) {
      const float ob = redB[w * 64 + tid];
      const float os = redS[w * 64 + tid];
      const float oi = redI[w * 64 + tid];
      const bool take = (ob < b) || (ob == b && oi < ix);
      const float loser = take ? b : ob;
      b = take ? ob : b;
      ix = take ? oi : ix;
      sec = fminf(fminf(sec, os), loser);
    }
    out_idx[m0 + tid] = ix;
    lidxs[tid] = ix;
    if (sec - b < MARGIN) {  // ambiguous -> parallel exact rescan
      kmin[m0 + tid] = ~0ull;
      const int p = atomicAdd(qcnt, 1);
      qtok[p] = m0 + tid;
    }
  }
  __syncthreads();

  // z_q gather for this block's 64 tokens.
  const int tl = tid >> 2, qp = tid & 3;
  const int code = (int)lidxs[tl];
  const float4* src = (const float4*)(cb + (size_t)code * DIM);
  float4* dst = (float4*)(out_zq + (size_t)(m0 + tl) * DIM);
  #pragma unroll
  for (int p = 0; p < 8; ++p) dst[qp + p * 4] = src[qp + p * 4];
}

// -------------------------------------------------------------------------
// Parallel exact rescan: block b handles (token slot b>>5, code chunk b&31).
// Each of 256 threads scores ONE code (chunk of 256 codes, 128 KB read),
// block-tree argmin, then atomicMin merge on packed (score,idx) key.
__global__ __launch_bounds__(256) void rescan_part_kernel(
    const float* __restrict__ ze, const float* __restrict__ cb,
    const float* __restrict__ cnorm, const int* __restrict__ qcnt,
    const int* __restrict__ qtok, unsigned long long* __restrict__ kmin) {
  __shared__ float xsh[DIM];
  __shared__ float rs[256];
  __shared__ int ri[256];
  const int tid = threadIdx.x;
  const int chunk = blockIdx.x & 31;
  const int n = *qcnt;
  for (int qi = blockIdx.x >> 5; qi < n; qi += (gridDim.x >> 5)) {
    const int token = qtok[qi];
    __syncthreads();
    if (tid < 32)
      ((float4*)xsh)[tid] = ((const float4*)(ze + (size_t)token * DIM))[tid];
    __syncthreads();
    const int code = chunk * 256 + tid;
    const float* crow = cb + (size_t)code * DIM;
    float dot = 0.f;
    #pragma unroll
    for (int d = 0; d < DIM; ++d) dot = fmaf(xsh[d], crow[d], dot);
    rs[tid] = fmaf(-2.f, dot, cnorm[code]);
    ri[tid] = code;
    __syncthreads();
    #pragma unroll
    for (int off = 128; off > 0; off >>= 1) {
      if (tid < off) {
        const float so = rs[tid + off];
        const int io = ri[tid + off];
        if (so < rs[tid] || (so == rs[tid] && io < ri[tid])) {
          rs[tid] = so; ri[tid] = io;
        }
      }
      __syncthreads();
    }
    if (tid == 0) {
      union { float f; unsigned int u; } c; c.f = rs[0];
      const unsigned int m = (c.u >> 31) ? ~c.u : (c.u | 0x80000000u);
      const unsigned long long key =
          ((unsigned long long)m << 32) | (unsigned int)ri[0];
      atomicMin(&kmin[token], key);
    }
    __syncthreads();
  }
}

// -------------------------------------------------------------------------
// Apply rescan results: decode keys, rewrite idx + z_q rows.
__global__ __launch_bounds__(256) void rescan_apply_kernel(
    const float* __restrict__ cb, const int* __restrict__ qcnt,
    const int* __restrict__ qtok, const unsigned long long* __restrict__ kmin,
    float* __restrict__ out_zq, float* __restrict__ out_idx) {
  const int tid = threadIdx.x;
  const int n = *qcnt;
  for (int qi = blockIdx.x; qi < n; qi += gridDim.x) {
    const int token = qtok[qi];
    const int code = (int)(unsigned int)(kmin[token] & 0xFFFFFFFFull);
    if (tid == 0) out_idx[token] = (float)code;
    if (tid < 32)
      ((float4*)(out_zq + (size_t)token * DIM))[tid] =
          ((const float4*)(cb + (size_t)code * DIM))[tid];
  }
}

// -------------------------------------------------------------------------
extern "C" void kernel_launch(void* const* d_in, const int* in_sizes, int n_in,
                              void* d_out, int out_size, void* d_ws,
                              size_t ws_size, hipStream_t stream) {
  const float* ze = (const float*)d_in[0];
  const float* cb = (const float*)d_in[1];
  float* out = (float*)d_out;

  unsigned short* Cs = (unsigned short*)d_ws;
  float* cnorm = (float*)((char*)d_ws + CNORM_OFF);
  int* qcnt = (int*)((char*)d_ws + QCNT_OFF);
  int* qtok = (int*)((char*)d_ws + QTOK_OFF);
  unsigned long long* kmin = (unsigned long long*)((char*)d_ws + KMIN_OFF);

  prep_kernel<<<KCODES / 4, 256, 0, stream>>>(cb, Cs, cnorm, qcnt);
  vq_mfma_kernel<<<M_TOK / BM, 256, 0, stream>>>(
      ze, Cs, cnorm, cb, qcnt, qtok, kmin, out, out + (size_t)M_TOK * DIM);
  rescan_part_kernel<<<4096, 256, 0, stream>>>(ze, cb, cnorm, qcnt, qtok,
                                               kmin);
  rescan_apply_kernel<<<256, 256, 0, stream>>>(cb, qcnt, qtok, kmin, out,
                                               out + (size_t)M_TOK * DIM);
}

// Round 6
// 269.143 us; speedup vs baseline: 3.9653x; 1.0574x over previous
//
#include <hip/hip_runtime.h>

// VQ argmin: 1-pass f16 SCREEN on matrix cores (xh.ch only, score error
// sigma ~9e-3) + exact fp32 parallel rescan for tokens whose screen
// best2-best1 gap < MARGIN (expected ~1.5% of tokens). Verified R2/R4/R5
// building blocks: 2-barrier staging K-loop (now 2 slices per barrier pair),
// seg-XOR LDS swizzles, packed-key atomicMin rescan merge.

#define M_TOK  32768
#define DIM    128
#define KCODES 8192
#define BM     64
#define NT     (KCODES / 256)   // 32 n-tiles per block
#define MARGIN 0.10f            // ~8 sigma of screen pair error; gap scale 6.9

typedef _Float16 half8v __attribute__((ext_vector_type(8)));
typedef float float4v __attribute__((ext_vector_type(4)));

union H2U { _Float16 h; unsigned short u; };
__device__ __forceinline__ unsigned short f2h_bits(_Float16 h) {
  H2U c; c.h = h; return c.u;
}

__device__ __forceinline__ void gload_lds16(const void* g, void* l) {
  __builtin_amdgcn_global_load_lds(
      (const __attribute__((address_space(1))) unsigned int*)g,
      (__attribute__((address_space(3))) unsigned int*)l, 16, 0, 0);
}

// ws layout: Cs f16[K][128] (hi only) | cnorm f32[K] | qcnt | qtok | kmin
#define CNORM_OFF  (KCODES * 256)
#define QCNT_OFF   (CNORM_OFF + KCODES * 4)
#define QTOK_OFF   (QCNT_OFF + 64)
#define KMIN_OFF   (QTOK_OFF + M_TOK * 4)

// -------------------------------------------------------------------------
// prep: exact fp32 cnorm + f16-hi codebook rows. Zeroes qcnt.
__global__ __launch_bounds__(256) void prep_kernel(
    const float* __restrict__ cb, unsigned short* __restrict__ Cs,
    float* __restrict__ cnorm, int* __restrict__ qcnt) {
  if (blockIdx.x == 0 && threadIdx.x == 0) *qcnt = 0;
  const int k = blockIdx.x * 4 + (threadIdx.x >> 6);
  const int lane = threadIdx.x & 63;
  const float2 v = ((const float2*)(cb + (size_t)k * DIM))[lane];
  float s = v.x * v.x + v.y * v.y;
  #pragma unroll
  for (int off = 32; off > 0; off >>= 1) s += __shfl_down(s, off);
  if (lane == 0) cnorm[k] = s;
  ushort2 hi;
  hi.x = f2h_bits((_Float16)v.x);
  hi.y = f2h_bits((_Float16)v.y);
  *(ushort2*)(Cs + (size_t)k * 128 + lane * 2) = hi;
}

// -------------------------------------------------------------------------
__global__ __launch_bounds__(256, 2) void vq_mfma_kernel(
    const float* __restrict__ ze, const unsigned short* __restrict__ Cs,
    const float* __restrict__ cnorm, const float* __restrict__ cb,
    int* __restrict__ qcnt, int* __restrict__ qtok,
    unsigned long long* __restrict__ kmin,
    float* __restrict__ out_zq, float* __restrict__ out_idx) {
  __shared__ char lds[49152];
  char* const As = lds;            // 16 KB: 64 rows x 256 B, seg-XOR swizzled
  char* const Bs = lds + 16384;    // 32 KB: 4 waves x 8 KB (2 slice bufs)

  const int tid = threadIdx.x;
  const int wn = tid >> 6;
  const int lane = tid & 63;
  const int quad = lane >> 4;
  const int l15 = lane & 15;
  const int m0 = blockIdx.x * BM;

  // Per-lane B-staging source offsets (R2/R4-verified mapping, hi-only rows:
  // 256 B stride). Dest slot s of local row r holds source seg s^((r>>1)&3).
  int loffC[4];
  #pragma unroll
  for (int c = 0; c < 4; ++c) {
    const int r = c * 16 + (lane >> 2);
    const int s = lane & 3;
    const int seg = s ^ ((r >> 1) & 3);
    loffC[c] = (wn * 64 + r) * 256 + seg * 16;
  }
  int boff[4];
  #pragma unroll
  for (int j = 0; j < 4; ++j) {
    const int n = j * 16 + l15;
    boff[j] = n * 64 + ((quad ^ ((n >> 1) & 3)) << 4);
  }
  char* const BsW = Bs + wn * 8192;

  // ---- stage As (hi only): fp32 -> f16, seg = (c>>3) ^ (r&7), 256 B rows --
  {
    const int r = tid >> 2;
    const int qh = tid & 3;
    const float* zrow = ze + (size_t)(m0 + r) * DIM + qh * 32;
    char* arow = As + r * 256;
    const int rx = r & 7;
    #pragma unroll
    for (int i = 0; i < 8; ++i) {
      const float4 v = *(const float4*)(zrow + i * 4);
      ushort4 hh;
      hh.x = f2h_bits((_Float16)v.x);
      hh.y = f2h_bits((_Float16)v.y);
      hh.z = f2h_bits((_Float16)v.z);
      hh.w = f2h_bits((_Float16)v.w);
      const int c = qh * 32 + i * 4;
      *(ushort4*)(arow + ((((c >> 3) ^ rx) << 4) | ((c & 7) << 1))) = hh;
    }
  }
  __syncthreads();

  // Preload all A-hi fragments into registers (reused for all 32 n-tiles).
  half8v ahi[4][4];
  #pragma unroll
  for (int ks = 0; ks < 4; ++ks)
    #pragma unroll
    for (int i = 0; i < 4; ++i) {
      const int m = i * 16 + l15;
      const int kslot = ks * 4 + quad;
      ahi[ks][i] = *(const half8v*)(As + m * 256 + ((kslot ^ (m & 7)) << 4));
    }

  float bestv[16], secv[16], idxv[16];
  #pragma unroll
  for (int s = 0; s < 16; ++s) {
    bestv[s] = 3.4e38f; secv[s] = 3.4e38f; idxv[s] = 0.f;
  }

  for (int nt = 0; nt < NT; ++nt) {
    const char* const tile = (const char*)Cs + (size_t)nt * 65536;
    float cnv[4];
    #pragma unroll
    for (int j = 0; j < 4; ++j)
      cnv[j] = cnorm[nt * 256 + wn * 64 + j * 16 + l15];

    float4v acc[4][4];
    #pragma unroll
    for (int i = 0; i < 4; ++i)
      #pragma unroll
      for (int j = 0; j < 4; ++j) acc[i][j] = (float4v)0.0f;

    // 4 k-slices per tile, staged TWO per barrier pair (halves drain count).
    #pragma unroll
    for (int t = 0; t < 2; ++t) {
      __syncthreads();  // prior pair consumed before DMA overwrite
      #pragma unroll
      for (int p = 0; p < 2; ++p)
        #pragma unroll
        for (int c = 0; c < 4; ++c)
          gload_lds16(tile + (t * 2 + p) * 64 + loffC[c],
                      BsW + p * 4096 + c * 1024);
      __syncthreads();  // drains vmcnt -> both slices ready

      #pragma unroll
      for (int p = 0; p < 2; ++p) {
        const int kk = t * 2 + p;
        half8v bf[4];
        #pragma unroll
        for (int j = 0; j < 4; ++j)
          bf[j] = *(const half8v*)(BsW + p * 4096 + boff[j]);
        #pragma unroll
        for (int i = 0; i < 4; ++i)
          #pragma unroll
          for (int j = 0; j < 4; ++j)
            acc[i][j] = __builtin_amdgcn_mfma_f32_16x16x32_f16(
                ahi[kk][i], bf[j], acc[i][j], 0, 0, 0);
      }
    }

    // Fold screen scores. Ascending n, strict < -> lowest index on ties.
    #pragma unroll
    for (int j = 0; j < 4; ++j) {
      const float nidx = (float)(nt * 256 + wn * 64 + j * 16 + l15);
      const float cn = cnv[j];
      #pragma unroll
      for (int i = 0; i < 4; ++i)
        #pragma unroll
        for (int rg = 0; rg < 4; ++rg) {
          const float sc = fmaf(-2.0f, acc[i][j][rg], cn);
          const int slot = i * 4 + rg;
          const bool bt = sc < bestv[slot];
          secv[slot] = bt ? bestv[slot] : fminf(secv[slot], sc);
          idxv[slot] = bt ? nidx : idxv[slot];
          bestv[slot] = bt ? sc : bestv[slot];
        }
    }
  }

  // Cross-lane reduce (16 lanes per token row, tie -> lowest index).
  #pragma unroll
  for (int slot = 0; slot < 16; ++slot) {
    float b = bestv[slot], sec = secv[slot], ix = idxv[slot];
    #pragma unroll
    for (int mk = 1; mk <= 8; mk <<= 1) {
      const float ob = __shfl_xor(b, mk);
      const float os = __shfl_xor(sec, mk);
      const float oi = __shfl_xor(ix, mk);
      const bool take = (ob < b) || (ob == b && oi < ix);
      const float loser = take ? b : ob;
      b = take ? ob : b;
      ix = take ? oi : ix;
      sec = fminf(fminf(sec, os), loser);
    }
    bestv[slot] = b; secv[slot] = sec; idxv[slot] = ix;
  }

  // Cross-wave merge via LDS (reuse As region after barrier).
  __syncthreads();
  float* const redB = (float*)lds;
  float* const redS = redB + 256;
  float* const redI = redB + 512;
  float* const lidxs = redB + 768;
  if (l15 == 0) {
    #pragma unroll
    for (int slot = 0; slot < 16; ++slot) {
      const int row = (slot >> 2) * 16 + quad * 4 + (slot & 3);
      redB[wn * 64 + row] = bestv[slot];
      redS[wn * 64 + row] = secv[slot];
      redI[wn * 64 + row] = idxv[slot];
    }
  }
  __syncthreads();
  if (tid < 64) {
    float b = redB[tid], sec = redS[tid], ix = redI[tid];
    #pragma unroll
    for (int w = 1; w < 4; ++w) {
      const float ob = redB[w * 64 + tid];
      const float os = redS[w * 64 + tid];
      const float oi = redI[w * 64 + tid];
      const bool take = (ob < b) || (ob == b && oi < ix);
      const float loser = take ? b : ob;
      b = take ? ob : b;
      ix = take ? oi : ix;
      sec = fminf(fminf(sec, os), loser);
    }
    out_idx[m0 + tid] = ix;
    lidxs[tid] = ix;
    if (sec - b < MARGIN) {  // ambiguous under screen error -> exact rescan
      kmin[m0 + tid] = ~0ull;
      const int p = atomicAdd(qcnt, 1);
      qtok[p] = m0 + tid;
    }
  }
  __syncthreads();

  // Provisional z_q gather for this block's 64 tokens.
  const int tl = tid >> 2, qp = tid & 3;
  const int code = (int)lidxs[tl];
  const float4* src = (const float4*)(cb + (size_t)code * DIM);
  float4* dst = (float4*)(out_zq + (size_t)(m0 + tl) * DIM);
  #pragma unroll
  for (int p = 0; p < 8; ++p) dst[qp + p * 4] = src[qp + p * 4];
}

// -------------------------------------------------------------------------
// Parallel exact rescan: block b handles (token slot b>>5, code chunk b&31).
// Each of 256 threads scores ONE code, block-tree argmin, atomicMin merge
// on packed (score,idx) key (monotone map: lower score -> smaller key).
__global__ __launch_bounds__(256) void rescan_part_kernel(
    const float* __restrict__ ze, const float* __restrict__ cb,
    const float* __restrict__ cnorm, const int* __restrict__ qcnt,
    const int* __restrict__ qtok, unsigned long long* __restrict__ kmin) {
  __shared__ float xsh[DIM];
  __shared__ float rs[256];
  __shared__ int ri[256];
  const int tid = threadIdx.x;
  const int chunk = blockIdx.x & 31;
  const int n = *qcnt;
  for (int qi = blockIdx.x >> 5; qi < n; qi += (gridDim.x >> 5)) {
    const int token = qtok[qi];
    __syncthreads();
    if (tid < 32)
      ((float4*)xsh)[tid] = ((const float4*)(ze + (size_t)token * DIM))[tid];
    __syncthreads();
    const int code = chunk * 256 + tid;
    const float* crow = cb + (size_t)code * DIM;
    float dot = 0.f;
    #pragma unroll
    for (int d = 0; d < DIM; ++d) dot = fmaf(xsh[d], crow[d], dot);
    rs[tid] = fmaf(-2.f, dot, cnorm[code]);
    ri[tid] = code;
    __syncthreads();
    #pragma unroll
    for (int off = 128; off > 0; off >>= 1) {
      if (tid < off) {
        const float so = rs[tid + off];
        const int io = ri[tid + off];
        if (so < rs[tid] || (so == rs[tid] && io < ri[tid])) {
          rs[tid] = so; ri[tid] = io;
        }
      }
      __syncthreads();
    }
    if (tid == 0) {
      union { float f; unsigned int u; } c; c.f = rs[0];
      const unsigned int m = (c.u >> 31) ? ~c.u : (c.u | 0x80000000u);
      const unsigned long long key =
          ((unsigned long long)m << 32) | (unsigned int)ri[0];
      atomicMin(&kmin[token], key);
    }
    __syncthreads();
  }
}

// -------------------------------------------------------------------------
// Apply rescan results: decode keys, rewrite idx + z_q rows.
__global__ __launch_bounds__(256) void rescan_apply_kernel(
    const float* __restrict__ cb, const int* __restrict__ qcnt,
    const int* __restrict__ qtok, const unsigned long long* __restrict__ kmin,
    float* __restrict__ out_zq, float* __restrict__ out_idx) {
  const int tid = threadIdx.x;
  const int n = *qcnt;
  for (int qi = blockIdx.x; qi < n; qi += gridDim.x) {
    const int token = qtok[qi];
    const int code = (int)(unsigned int)(kmin[token] & 0xFFFFFFFFull);
    if (tid == 0) out_idx[token] = (float)code;
    if (tid < 32)
      ((float4*)(out_zq + (size_t)token * DIM))[tid] =
          ((const float4*)(cb + (size_t)code * DIM))[tid];
  }
}

// -------------------------------------------------------------------------
extern "C" void kernel_launch(void* const* d_in, const int* in_sizes, int n_in,
                              void* d_out, int out_size, void* d_ws,
                              size_t ws_size, hipStream_t stream) {
  const float* ze = (const float*)d_in[0];
  const float* cb = (const float*)d_in[1];
  float* out = (float*)d_out;

  unsigned short* Cs = (unsigned short*)d_ws;
  float* cnorm = (float*)((char*)d_ws + CNORM_OFF);
  int* qcnt = (int*)((char*)d_ws + QCNT_OFF);
  int* qtok = (int*)((char*)d_ws + QTOK_OFF);
  unsigned long long* kmin = (unsigned long long*)((char*)d_ws + KMIN_OFF);

  prep_kernel<<<KCODES / 4, 256, 0, stream>>>(cb, Cs, cnorm, qcnt);
  vq_mfma_kernel<<<M_TOK / BM, 256, 0, stream>>>(
      ze, Cs, cnorm, cb, qcnt, qtok, kmin, out, out + (size_t)M_TOK * DIM);
  rescan_part_kernel<<<4096, 256, 0, stream>>>(ze, cb, cnorm, qcnt, qtok,
                                               kmin);
  rescan_apply_kernel<<<256, 256, 0, stream>>>(cb, qcnt, qtok, kmin, out,
                                               out + (size_t)M_TOK * DIM);
}